// Round 1
// baseline (97.364 us; speedup 1.0000x reference)
//
#include <hip/hip_runtime.h>

#define DIM   4096
#define RANK  16
#define ROWS  4      // rows of x per block
#define NT    512    // 8 waves: rank-group = w&3, d-half = w>>2
#define NWAVE 8

typedef int   int2v  __attribute__((ext_vector_type(2)));
typedef float f32x4v __attribute__((ext_vector_type(4)));

__device__ __forceinline__ float f4get(const float4& v, int j) {
    switch (j) { case 0: return v.x; case 1: return v.y; case 2: return v.z; default: return v.w; }
}

// ---- tiny setup kernel: Ut[q][d] = U[d][q] * nw[d]  (norm_weight folded in) ----
__global__ __launch_bounds__(256) void transpose_U(const float* __restrict__ U,
                                                   const float* __restrict__ nw,
                                                   float* __restrict__ Ut) {
    const int d = blockIdx.x * 256 + threadIdx.x;   // 4096 threads total
    const float wv = nw[d];
    const float4* U4 = (const float4*)U;
    float4 u0 = U4[(size_t)d * 4 + 0];
    float4 u1 = U4[(size_t)d * 4 + 1];
    float4 u2 = U4[(size_t)d * 4 + 2];
    float4 u3 = U4[(size_t)d * 4 + 3];
    Ut[ 0*DIM + d] = u0.x*wv; Ut[ 1*DIM + d] = u0.y*wv; Ut[ 2*DIM + d] = u0.z*wv; Ut[ 3*DIM + d] = u0.w*wv;
    Ut[ 4*DIM + d] = u1.x*wv; Ut[ 5*DIM + d] = u1.y*wv; Ut[ 6*DIM + d] = u1.z*wv; Ut[ 7*DIM + d] = u1.w*wv;
    Ut[ 8*DIM + d] = u2.x*wv; Ut[ 9*DIM + d] = u2.y*wv; Ut[10*DIM + d] = u2.z*wv; Ut[11*DIM + d] = u2.w*wv;
    Ut[12*DIM + d] = u3.x*wv; Ut[13*DIM + d] = u3.y*wv; Ut[14*DIM + d] = u3.z*wv; Ut[15*DIM + d] = u3.w*wv;
}

// No x LDS staging: x reads come from global (L1/L2 serve the 4x rank-group
// reuse within a block; Phase-B residual re-read is L2-hot). LDS shrinks from
// 65 KB -> ~1 KB, lifting residency from 2 blocks/CU (16 waves) to 4 (32 waves).
__global__ __launch_bounds__(NT, 8) void arl_fused(
    const float* __restrict__ x,  const float* __restrict__ Ut,
    const float* __restrict__ S,  const float* __restrict__ V,
    const float* __restrict__ gamma, float* __restrict__ out)
{
    const int t    = threadIdx.x;
    const int w    = t >> 6;
    const int lane = t & 63;
    const int rg   = w & 3;       // rank group: ranks [4rg, 4rg+4)
    const int dh   = w >> 2;      // d-half: float4 cols [dh*512, dh*512+512)
    const size_t row0 = (size_t)blockIdx.x * ROWS;

    const float4* x4   = (const float4*)(x + row0 * DIM);
    float4*       out4 = (float4*)(out + row0 * DIM);
    const float4* Ut4  = (const float4*)Ut;    // [q][d/4], nw pre-folded
    const float4* V4   = (const float4*)V;     // [q][d/4]
    const float4* g4   = (const float4*)gamma;

    __shared__ float s_ssq[NWAVE][ROWS];
    __shared__ float s_hraw[NWAVE][16];
    __shared__ __align__(16) float s_h[ROWS * RANK];

    // ---- Phase A: wave (rg,dh) accumulates its 4 ranks over its d-half ----
    // v[r*4+ql] = sum_{d in half} x[r][d] * Ut[4rg+ql][d]   (rstd folded later)
    float v[16];
    #pragma unroll
    for (int i = 0; i < 16; ++i) v[i] = 0.f;
    float ssq[ROWS] = {0.f, 0.f, 0.f, 0.f};

    #pragma unroll 1
    for (int k = 0; k < 8; ++k) {
        const int d4 = dh * 512 + k * 64 + lane;
        float4 u[4];
        #pragma unroll
        for (int ql = 0; ql < 4; ++ql)
            u[ql] = Ut4[(size_t)(rg * 4 + ql) * (DIM/4) + d4];   // coalesced, L2-resident
        float4 xr[ROWS];
        #pragma unroll
        for (int r = 0; r < ROWS; ++r) xr[r] = x4[(size_t)r * (DIM/4) + d4];  // cached global
        #pragma unroll
        for (int j = 0; j < 4; ++j) {
            float xj[ROWS];
            #pragma unroll
            for (int r = 0; r < ROWS; ++r) {
                xj[r] = f4get(xr[r], j);
                ssq[r] = fmaf(xj[r], xj[r], ssq[r]);
            }
            #pragma unroll
            for (int ql = 0; ql < 4; ++ql) {
                const float uj = f4get(u[ql], j);
                #pragma unroll
                for (int r = 0; r < ROWS; ++r)
                    v[r*4+ql] = fmaf(xj[r], uj, v[r*4+ql]);
            }
        }
    }

    // ---- ssq wave-reduce (partial over this wave's d-half) ----
    #pragma unroll
    for (int r = 0; r < ROWS; ++r) {
        float s = ssq[r];
        #pragma unroll
        for (int off = 32; off >= 1; off >>= 1) s += __shfl_xor(s, off, 64);
        if (lane == 0) s_ssq[w][r] = s;
    }

    // ---- packed wave reduction of v[16] over 64 lanes (proven R4-R9) ----
    #pragma unroll
    for (int i = 0; i < 8; ++i) {
        int a = __float_as_int(v[2*i]);
        int b = __float_as_int(v[2*i+1]);
        int2v pr = __builtin_amdgcn_permlane32_swap(a, b, false, false);
        v[i] = __int_as_float(pr.x) + __int_as_float(pr.y);
    }
    #pragma unroll
    for (int s = 1; s <= 3; ++s) {
        const int off = 32 >> s;
        const int n   = 8 >> s;
        const bool hi = (lane >> (5 - s)) & 1;
        #pragma unroll
        for (int i = 0; i < n; ++i) {
            float lo = v[2*i], hg = v[2*i+1];
            float slo = __shfl_xor(lo, off, 64);
            float shg = __shfl_xor(hg, off, 64);
            v[i] = hi ? (hg + shg) : (lo + slo);
        }
    }
    v[0] += __shfl_xor(v[0], 2, 64);
    v[0] += __shfl_xor(v[0], 1, 64);
    {
        const int idx = ((lane >> 5) & 1) | (((lane >> 4) & 1) << 1)
                      | (((lane >> 3) & 1) << 2) | (((lane >> 2) & 1) << 3);
        if ((lane & 3) == 0) s_hraw[w][idx] = v[0];
    }
    __syncthreads();

    // ---- combine d-halves; fold in rstd[r] and S*keep; publish s_h[r][q] ----
    if (t < 64) {
        const int r = t >> 4, q = t & 15;
        const int qg = q >> 2, ql = q & 3;
        const float hs = s_hraw[qg][r * 4 + ql] + s_hraw[qg + 4][r * 4 + ql];
        const float tot_ssq = s_ssq[0][r] + s_ssq[4][r];   // rg==0 waves only
        const float rstd = rsqrtf(tot_ssq * (1.0f / DIM) + 1e-6f);
        float tot = 0.f;
        #pragma unroll
        for (int i = 0; i < RANK; ++i) tot += fabsf(S[i]);
        const float denom = fmaxf(tot, 1e-8f);
        float cum = 0.f, se = 0.f;
        #pragma unroll
        for (int i = 0; i < RANK; ++i) {
            if (i == q) se = ((cum / denom) < 0.95f) ? S[i] : 0.f;
            cum += fabsf(S[i]);
        }
        s_h[t] = hs * se * rstd;
    }
    __syncthreads();

    // ---- Phase B: out[d] = x[d] + gamma[d] * sum_q h[r][q]*V[q][d] ----
    const float4* s_h4 = (const float4*)s_h;
    #pragma unroll 1
    for (int k = 0; k < 2; ++k) {
        const int c = k * NT + t;
        float4 acc[ROWS];
        #pragma unroll
        for (int r = 0; r < ROWS; ++r) acc[r] = make_float4(0.f, 0.f, 0.f, 0.f);
        #pragma unroll 1
        for (int qg = 0; qg < 4; ++qg) {
            float4 vv[4];
            #pragma unroll
            for (int ql = 0; ql < 4; ++ql)
                vv[ql] = V4[(size_t)(qg*4 + ql) * (DIM/4) + c];
            #pragma unroll
            for (int r = 0; r < ROWS; ++r) {
                const float4 hq = s_h4[r * 4 + qg];   // LDS broadcast
                #pragma unroll
                for (int ql = 0; ql < 4; ++ql) {
                    const float hqq = f4get(hq, ql);
                    acc[r].x = fmaf(hqq, vv[ql].x, acc[r].x);
                    acc[r].y = fmaf(hqq, vv[ql].y, acc[r].y);
                    acc[r].z = fmaf(hqq, vv[ql].z, acc[r].z);
                    acc[r].w = fmaf(hqq, vv[ql].w, acc[r].w);
                }
            }
        }
        const float4 g = g4[c];
        #pragma unroll
        for (int r = 0; r < ROWS; ++r) {
            const float4 xrr = x4[(size_t)r * (DIM/4) + c];   // residual: L2-hot re-read
            float4 o;
            o.x = fmaf(g.x, acc[r].x, xrr.x);
            o.y = fmaf(g.y, acc[r].y, xrr.y);
            o.z = fmaf(g.z, acc[r].z, xrr.z);
            o.w = fmaf(g.w, acc[r].w, xrr.w);
            __builtin_nontemporal_store(*(const f32x4v*)&o,
                                        (f32x4v*)(out4 + (size_t)r * (DIM/4) + c));
        }
    }
}

extern "C" void kernel_launch(void* const* d_in, const int* in_sizes, int n_in,
                              void* d_out, int out_size, void* d_ws, size_t ws_size,
                              hipStream_t stream) {
    (void)in_sizes; (void)n_in; (void)ws_size;
    const float* x  = (const float*)d_in[0];
    const float* U  = (const float*)d_in[1];
    const float* S  = (const float*)d_in[2];
    const float* V  = (const float*)d_in[3];
    const float* nw = (const float*)d_in[4];
    const float* g  = (const float*)d_in[5];
    float* out = (float*)d_out;
    float* Ut  = (float*)d_ws;                 // 256 KB scratch

    hipLaunchKernelGGL(transpose_U, dim3(DIM / 256), dim3(256), 0, stream, U, nw, Ut);

    const int rows = out_size / DIM;           // 8192
    const int grid = rows / ROWS;              // 2048
    hipLaunchKernelGGL(arl_fused, dim3(grid), dim3(NT), 0, stream,
                       x, Ut, S, V, g, out);
}

// Round 3
// 85.327 us; speedup vs baseline: 1.1411x; 1.1411x over previous
//
#include <hip/hip_runtime.h>

#define DIM   4096
#define RANK  16
#define ROWS  4      // rows of x per block
#define NT    512    // 8 waves: rank-group = w&3, d-half = w>>2
#define NWAVE 8

typedef __fp16 f16;
typedef __fp16 f16x2 __attribute__((ext_vector_type(2)));
typedef __fp16 f16x4 __attribute__((ext_vector_type(4)));
typedef __fp16 f16x8 __attribute__((ext_vector_type(8)));
typedef int    int2v  __attribute__((ext_vector_type(2)));
typedef float  f32x4v __attribute__((ext_vector_type(4)));

__device__ __forceinline__ float fdot2f(f16x2 a, f16x2 b, float c) {
    return __builtin_amdgcn_fdot2(a, b, c, false);   // v_dot2_f32_f16
}

// slice i-th f16x2 out of an int4-viewed f16x8; selector folds under full unroll
__device__ __forceinline__ f16x2 h2get(const int4& v, int i) {
    int w;
    switch (i) { case 0: w = v.x; break; case 1: w = v.y; break;
                 case 2: w = v.z; break; default: w = v.w; }
    return __builtin_bit_cast(f16x2, w);
}

// ---- setup kernel: Ut[q][d] = f16(U[d][q]*nw[d]);  Vp[d][q] = f16(V[q][d]) ----
__global__ __launch_bounds__(256) void prep_weights(const float* __restrict__ U,
                                                    const float* __restrict__ nw,
                                                    const float* __restrict__ V,
                                                    f16* __restrict__ Ut,
                                                    f16* __restrict__ Vp) {
    const int d = blockIdx.x * 256 + threadIdx.x;   // 4096 threads total
    const float wv = nw[d];
    const float4* U4 = (const float4*)U;
    const float4 u0 = U4[(size_t)d * 4 + 0];
    const float4 u1 = U4[(size_t)d * 4 + 1];
    const float4 u2 = U4[(size_t)d * 4 + 2];
    const float4 u3 = U4[(size_t)d * 4 + 3];
    Ut[ 0*DIM + d] = (f16)(u0.x*wv); Ut[ 1*DIM + d] = (f16)(u0.y*wv);
    Ut[ 2*DIM + d] = (f16)(u0.z*wv); Ut[ 3*DIM + d] = (f16)(u0.w*wv);
    Ut[ 4*DIM + d] = (f16)(u1.x*wv); Ut[ 5*DIM + d] = (f16)(u1.y*wv);
    Ut[ 6*DIM + d] = (f16)(u1.z*wv); Ut[ 7*DIM + d] = (f16)(u1.w*wv);
    Ut[ 8*DIM + d] = (f16)(u2.x*wv); Ut[ 9*DIM + d] = (f16)(u2.y*wv);
    Ut[10*DIM + d] = (f16)(u2.z*wv); Ut[11*DIM + d] = (f16)(u2.w*wv);
    Ut[12*DIM + d] = (f16)(u3.x*wv); Ut[13*DIM + d] = (f16)(u3.y*wv);
    Ut[14*DIM + d] = (f16)(u3.z*wv); Ut[15*DIM + d] = (f16)(u3.w*wv);
    f16 vq[16];
    #pragma unroll
    for (int q = 0; q < 16; ++q) vq[q] = (f16)V[(size_t)q * DIM + d];  // coalesced per q
    f16x8 lo = { vq[0], vq[1], vq[2], vq[3], vq[4], vq[5], vq[6], vq[7] };
    f16x8 hi = { vq[8], vq[9], vq[10], vq[11], vq[12], vq[13], vq[14], vq[15] };
    f16x8* Vp8 = (f16x8*)Vp;
    Vp8[(size_t)d * 2 + 0] = lo;
    Vp8[(size_t)d * 2 + 1] = hi;
}

// fp16 projection path (error << out's fp32 ULP since h*gamma ~ 5e-7 vs x ~ 1):
// - x in LDS as fp16 (32 KB -> 3 blocks/CU), ssq in fp32 during staging
// - fp16 weights via v_dot2_f32_f16 (halves weight L2 traffic AND VALU work)
// - residual x re-read fp32 from global (L2-hot), out stores nontemporal
__global__ __launch_bounds__(NT, 6) void arl_fused(
    const float* __restrict__ x,  const f16* __restrict__ Ut,
    const float* __restrict__ S,  const f16* __restrict__ Vp,
    const float* __restrict__ gamma, float* __restrict__ out)
{
    const int t    = threadIdx.x;
    const int w    = t >> 6;
    const int lane = t & 63;
    const int rg   = w & 3;       // rank group: ranks [4rg, 4rg+4)
    const int dh   = w >> 2;      // d-half: f16x8 chunks [dh*256, dh*256+256)
    const size_t row0 = (size_t)blockIdx.x * ROWS;

    const float4* x4   = (const float4*)(x + row0 * DIM);
    float4*       out4 = (float4*)(out + row0 * DIM);
    const int4*   Ut16 = (const int4*)Ut;     // [16][512] f16x8-chunks
    const int4*   Vp16 = (const int4*)Vp;     // [4096][2]
    const float4* g4   = (const float4*)gamma;

    __shared__ __align__(16) f16 xh[ROWS * DIM];     // 32 KB fp16 x
    __shared__ float s_ssq[NWAVE][ROWS];
    __shared__ float s_hraw[NWAVE][16];
    __shared__ __align__(16) f16 s_hh[ROWS * RANK];  // 128 B fp16 h

    // ---- Stage x -> LDS (fp16) + fp32 ssq partials ----
    float ssqp[ROWS] = {0.f, 0.f, 0.f, 0.f};
    #pragma unroll
    for (int i = 0; i < 8; ++i) {
        const int idx = i * NT + t;            // 0..4095 float4-chunks
        const int r   = i >> 1;                // row of this chunk (static)
        const float4 val = x4[idx];
        ssqp[r] = fmaf(val.x, val.x, ssqp[r]);
        ssqp[r] = fmaf(val.y, val.y, ssqp[r]);
        ssqp[r] = fmaf(val.z, val.z, ssqp[r]);
        ssqp[r] = fmaf(val.w, val.w, ssqp[r]);
        f16x4 pk;
        pk.x = (f16)val.x; pk.y = (f16)val.y; pk.z = (f16)val.z; pk.w = (f16)val.w;
        ((f16x4*)xh)[idx] = pk;
    }
    __syncthreads();

    // ---- ssq wave-reduce (each thread has partials for all 4 rows) ----
    #pragma unroll
    for (int r = 0; r < ROWS; ++r) {
        float s = ssqp[r];
        #pragma unroll
        for (int off = 32; off >= 1; off >>= 1) s += __shfl_xor(s, off, 64);
        if (lane == 0) s_ssq[w][r] = s;
    }

    // ---- Phase A: wave (rg,dh) accumulates its 4 ranks over its d-half ----
    float v[16];
    #pragma unroll
    for (int i = 0; i < 16; ++i) v[i] = 0.f;

    #pragma unroll 1
    for (int k = 0; k < 4; ++k) {
        const int p = dh * 256 + k * 64 + lane;       // f16x8 chunk index
        int4 u[4];
        #pragma unroll
        for (int ql = 0; ql < 4; ++ql)
            u[ql] = Ut16[(size_t)(rg * 4 + ql) * 512 + p];   // coalesced 16B
        int4 xr[ROWS];
        #pragma unroll
        for (int r = 0; r < ROWS; ++r) xr[r] = ((const int4*)xh)[r * 512 + p];
        #pragma unroll
        for (int i = 0; i < 4; ++i) {
            f16x2 xp[ROWS];
            #pragma unroll
            for (int r = 0; r < ROWS; ++r) xp[r] = h2get(xr[r], i);
            #pragma unroll
            for (int ql = 0; ql < 4; ++ql) {
                const f16x2 up = h2get(u[ql], i);
                #pragma unroll
                for (int r = 0; r < ROWS; ++r)
                    v[r*4+ql] = fdot2f(xp[r], up, v[r*4+ql]);
            }
        }
    }

    // ---- packed wave reduction of v[16] over 64 lanes (proven R4-R9) ----
    #pragma unroll
    for (int i = 0; i < 8; ++i) {
        int a = __float_as_int(v[2*i]);
        int b = __float_as_int(v[2*i+1]);
        int2v pr = __builtin_amdgcn_permlane32_swap(a, b, false, false);
        v[i] = __int_as_float(pr.x) + __int_as_float(pr.y);
    }
    #pragma unroll
    for (int s = 1; s <= 3; ++s) {
        const int off = 32 >> s;
        const int n   = 8 >> s;
        const bool hi = (lane >> (5 - s)) & 1;
        #pragma unroll
        for (int i = 0; i < n; ++i) {
            float lo = v[2*i], hg = v[2*i+1];
            float slo = __shfl_xor(lo, off, 64);
            float shg = __shfl_xor(hg, off, 64);
            v[i] = hi ? (hg + shg) : (lo + slo);
        }
    }
    v[0] += __shfl_xor(v[0], 2, 64);
    v[0] += __shfl_xor(v[0], 1, 64);
    {
        const int idx = ((lane >> 5) & 1) | (((lane >> 4) & 1) << 1)
                      | (((lane >> 3) & 1) << 2) | (((lane >> 2) & 1) << 3);
        if ((lane & 3) == 0) s_hraw[w][idx] = v[0];
    }
    __syncthreads();

    // ---- combine d-halves; fold in rstd[r] and S*keep; publish s_hh (fp16) ----
    if (t < 64) {
        const int r = t >> 4, q = t & 15;
        const int qg = q >> 2, ql = q & 3;
        const float hs = s_hraw[qg][r * 4 + ql] + s_hraw[qg + 4][r * 4 + ql];
        float tot_ssq = 0.f;
        #pragma unroll
        for (int ww = 0; ww < NWAVE; ++ww) tot_ssq += s_ssq[ww][r];
        const float rstd = rsqrtf(tot_ssq * (1.0f / DIM) + 1e-6f);
        float tot = 0.f;
        #pragma unroll
        for (int i = 0; i < RANK; ++i) tot += fabsf(S[i]);
        const float denom = fmaxf(tot, 1e-8f);
        float cum = 0.f, se = 0.f;
        #pragma unroll
        for (int i = 0; i < RANK; ++i) {
            if (i == q) se = ((cum / denom) < 0.95f) ? S[i] : 0.f;
            cum += fabsf(S[i]);
        }
        s_hh[t] = (f16)(hs * se * rstd);
    }
    __syncthreads();

    // ---- Phase B: out[d] = x[d] + gamma[d] * sum_q h[r][q]*Vp[d][q] ----
    f16x2 hp[ROWS][8];
    {
        const int4* hh16 = (const int4*)s_hh;
        #pragma unroll
        for (int r = 0; r < ROWS; ++r) {
            const int4 a = hh16[r*2 + 0];
            const int4 b = hh16[r*2 + 1];
            #pragma unroll
            for (int i = 0; i < 4; ++i) {
                hp[r][i]     = h2get(a, i);
                hp[r][4 + i] = h2get(b, i);
            }
        }
    }
    #pragma unroll 1
    for (int k = 0; k < 2; ++k) {
        const int c = k * NT + t;                 // float4 column
        float4 xr[ROWS];                          // residual: issue early, L2-hot
        #pragma unroll
        for (int r = 0; r < ROWS; ++r) xr[r] = x4[(size_t)r * (DIM/4) + c];
        const float4 g = g4[c];
        float acc[ROWS][4];
        #pragma unroll
        for (int r = 0; r < ROWS; ++r)
            #pragma unroll
            for (int j = 0; j < 4; ++j) acc[r][j] = 0.f;
        #pragma unroll
        for (int j = 0; j < 4; ++j) {
            const int dd = c * 4 + j;
            const int4 v0 = Vp16[(size_t)dd * 2 + 0];
            const int4 v1 = Vp16[(size_t)dd * 2 + 1];
            #pragma unroll
            for (int r = 0; r < ROWS; ++r) {
                float a = acc[r][j];
                #pragma unroll
                for (int i = 0; i < 4; ++i)
                    a = fdot2f(hp[r][i], h2get(v0, i), a);
                #pragma unroll
                for (int i = 0; i < 4; ++i)
                    a = fdot2f(hp[r][4+i], h2get(v1, i), a);
                acc[r][j] = a;
            }
        }
        #pragma unroll
        for (int r = 0; r < ROWS; ++r) {
            float4 o;
            o.x = fmaf(g.x, acc[r][0], xr[r].x);
            o.y = fmaf(g.y, acc[r][1], xr[r].y);
            o.z = fmaf(g.z, acc[r][2], xr[r].z);
            o.w = fmaf(g.w, acc[r][3], xr[r].w);
            __builtin_nontemporal_store(*(const f32x4v*)&o,
                                        (f32x4v*)(out4 + (size_t)r * (DIM/4) + c));
        }
    }
}

extern "C" void kernel_launch(void* const* d_in, const int* in_sizes, int n_in,
                              void* d_out, int out_size, void* d_ws, size_t ws_size,
                              hipStream_t stream) {
    (void)in_sizes; (void)n_in; (void)ws_size;
    const float* x  = (const float*)d_in[0];
    const float* U  = (const float*)d_in[1];
    const float* S  = (const float*)d_in[2];
    const float* V  = (const float*)d_in[3];
    const float* nw = (const float*)d_in[4];
    const float* g  = (const float*)d_in[5];
    float* out = (float*)d_out;
    f16* Ut = (f16*)d_ws;                                   // 128 KB
    f16* Vp = (f16*)((char*)d_ws + 16 * DIM * sizeof(f16)); // 128 KB

    hipLaunchKernelGGL(prep_weights, dim3(DIM / 256), dim3(256), 0, stream,
                       U, nw, V, Ut, Vp);

    const int rows = out_size / DIM;           // 8192
    const int grid = rows / ROWS;              // 2048
    hipLaunchKernelGGL(arl_fused, dim3(grid), dim3(NT), 0, stream,
                       x, Ut, S, Vp, g, out);
}